// Round 24
// baseline (159.035 us; speedup 1.0000x reference)
//
#include <hip/hip_runtime.h>
#include <stdint.h>

typedef __attribute__((ext_vector_type(4))) float f32x4;
typedef __attribute__((ext_vector_type(4))) unsigned int u32x4;
typedef __attribute__((ext_vector_type(4))) int i32x4;

#define NB 16
#define NC 128
#define NH 128
#define NW 128
#define WP 130

__device__ __forceinline__ int swz7(int wp) { return (wp ^ (wp >> 3)) & 7; }

// ---------------- prep: wfrag (B sign bytes, i8) + sf = mean|w| + theta ----------------
// i8 K=64 layout (r16-validated): wfrag byte f = p*8192 + m*4096 + ni*1024 + l*16 + b
// o = ni*16 + (l&15), c = m*64 + (l>>4)*16 + b
__global__ __launch_bounds__(256) void k_prep(const float* __restrict__ cw,
                                              const float* __restrict__ b1,
                                              const float* __restrict__ pa,
                                              const float* __restrict__ b2,
                                              float* __restrict__ sf,
                                              float* __restrict__ theta,
                                              unsigned char* __restrict__ wf) {
    int b = blockIdx.x, t = threadIdx.x;    // 288 blocks
    int f = b * 256 + t;                    // < 73728
    int bb  = f & 15;
    int l   = (f >> 4) & 63;
    int ni  = (f >> 10) & 3;
    int m   = (f >> 12) & 1;
    int p   = f >> 13;
    int o = ni * 16 + (l & 15);
    int c = m * 64 + (l >> 4) * 16 + bb;
    float wv = cw[o * 1152 + c * 9 + p];
    wf[f] = wv > 0.f ? (unsigned char)0x01
                     : (wv < 0.f ? (unsigned char)0xFF : (unsigned char)0x00);
    if (b < 64) {                           // sf[b] = mean|w| over 1152
        __shared__ float red[4];
        const float* pp = cw + b * 1152;
        float s = 0.f;
        for (int i = t; i < 1152; i += 256) s += fabsf(pp[i]);
#pragma unroll
        for (int off = 32; off > 0; off >>= 1) s += __shfl_down(s, off);
        if ((t & 63) == 0) red[t >> 6] = s;
        __syncthreads();
        if (t == 0) sf[b] = (red[0] + red[1] + red[2] + red[3]) * (1.0f / 1152.0f);
    }
    if (b == 64 && t < NC) {                // theta: sign(prelu(v+b1)+b2) == sign(v - theta)
        float B1 = b1[t], A = pa[t], B2 = b2[t];   // prelu slope a>0 -> monotone
        theta[t] = (-B2 >= 0.f) ? (-B1 - B2) : (-B1 - B2 / A);
    }
}

__device__ __forceinline__ unsigned int pki8(float v, float th) {
    return v > th ? 0x01u : (v < th ? 0xFFu : 0u);
}

// ---------------- fused (r21 schedule, 1-row blocks, 3 blocks/CU):
// block = 1 output row x 128 cols; staging 3 padded rows = 49.9 KB LDS ->
// 3 blocks/CU (12 waves). Full 256B out lines kept; per-thread liveness <= r21
// (XA/XB/XC lookahead, single sc[8][4], acc[2][4]). All r21-proven mappings. ----
__global__ __launch_bounds__(256, 3) void k_fused(
    const float* __restrict__ x, const float* __restrict__ theta,
    const float* __restrict__ pw, const unsigned char* __restrict__ wf,
    const float* __restrict__ sf, float* __restrict__ out) {
    __shared__ __align__(16) unsigned char AT[49920];   // staging 3x130x128 | Tt 4x9216
    int bxr = blockIdx.x;                   // 2048
    int bx = (bxr & 7) * 256 + (bxr >> 3);  // XCD swizzle (2048 % 8 == 0, bijective)
    int nb = bx >> 7;
    int h  = bx & 127;                      // this block's output row
    int t = threadIdx.x;
    int wid = t >> 6;
    int l = t & 63;
    int lr = l & 15, lg = l >> 4;

    // ---- pad columns wp=0, 129 (always zero; 48 trivial stores) ----
    if (t < 48) {
        int rho = t >> 4, side = (t >> 3) & 1, u = t & 7;
        int wp = side ? (WP - 1) : 0;
        u32x4 z = {0u, 0u, 0u, 0u};
        *(u32x4*)(AT + (size_t)(rho * WP + wp) * NC + ((u ^ swz7(wp)) << 4)) = z;
    }

    // ---- staging: thread (w4 = t&31, cg = t>>5); all 3 rows in flight ----
    int w4 = t & 31, cg = t >> 5;
    const float* xbase = x + ((size_t)nb * NC + cg * 16) * (NH * NW) + 4 * w4;
    f32x4 th0 = *(const f32x4*)(theta + cg * 16);
    f32x4 th1 = *(const f32x4*)(theta + cg * 16 + 4);
    f32x4 th2 = *(const f32x4*)(theta + cg * 16 + 8);
    f32x4 th3 = *(const f32x4*)(theta + cg * 16 + 12);
    f32x4 p0 = *(const f32x4*)(pw + cg * 16);
    f32x4 p1 = *(const f32x4*)(pw + cg * 16 + 4);
    f32x4 p2 = *(const f32x4*)(pw + cg * 16 + 8);
    f32x4 p3 = *(const f32x4*)(pw + cg * 16 + 12);
    float pwv[16] = {p0.x, p0.y, p0.z, p0.w, p1.x, p1.y, p1.z, p1.w,
                     p2.x, p2.y, p2.z, p2.w, p3.x, p3.y, p3.z, p3.w};
    float sc[8][4];                         // shortcut regs, statically indexed
    f32x4 XA[16], XB[16], XC[16];

#define ISSUE(XR, HH) \
    { const float* xp = xbase + (size_t)(HH) * NW; \
      _Pragma("unroll") for (int cc = 0; cc < 16; ++cc) \
          XR[cc] = *(const f32x4*)(xp + (size_t)cc * (NH * NW)); }
#define PACKROWM(RHO, XR, EM) \
    _Pragma("unroll") for (int ww = 0; ww < 4; ++ww) { \
        int wp = 4 * w4 + ww + 1; \
        u32x4 v; \
        v.x = (pki8(XR[0][ww], th0.x) | (pki8(XR[1][ww], th0.y) << 8) | \
               (pki8(XR[2][ww], th0.z) << 16) | (pki8(XR[3][ww], th0.w) << 24)) & (EM); \
        v.y = (pki8(XR[4][ww], th1.x) | (pki8(XR[5][ww], th1.y) << 8) | \
               (pki8(XR[6][ww], th1.z) << 16) | (pki8(XR[7][ww], th1.w) << 24)) & (EM); \
        v.z = (pki8(XR[8][ww], th2.x) | (pki8(XR[9][ww], th2.y) << 8) | \
               (pki8(XR[10][ww], th2.z) << 16) | (pki8(XR[11][ww], th2.w) << 24)) & (EM); \
        v.w = (pki8(XR[12][ww], th3.x) | (pki8(XR[13][ww], th3.y) << 8) | \
               (pki8(XR[14][ww], th3.z) << 16) | (pki8(XR[15][ww], th3.w) << 24)) & (EM); \
        *(u32x4*)(AT + (size_t)((RHO) * WP + wp) * NC + ((cg ^ swz7(wp)) << 4)) = v; \
    }

    int hTop = (h > 0) ? (h - 1) : 0;       // clamped (masked to zero below)
    int hBot = (h < 127) ? (h + 1) : 127;
    unsigned emT = (h > 0) ? 0xFFFFFFFFu : 0u;
    unsigned emB = (h < 127) ? 0xFFFFFFFFu : 0u;

    ISSUE(XA, hTop)                         // all 48 loads in flight before any pack
    ISSUE(XB, h)
    ISSUE(XC, hBot)
    __builtin_amdgcn_sched_barrier(0);      // pin: issues may not sink below here
    PACKROWM(0, XA, emT)
    PACKROWM(1, XB, 0xFFFFFFFFu)
#pragma unroll
    for (int i = 0; i < 8; ++i) {           // shortcut from center row (XB)
        float wa = pwv[2 * i], wb = pwv[2 * i + 1];
#pragma unroll
        for (int ww = 0; ww < 4; ++ww)
            sc[i][ww] = wa * XB[2 * i][ww] + wb * XB[2 * i + 1][ww];
    }
    PACKROWM(2, XC, emB)

    float sfr[4];
#pragma unroll
    for (int ni = 0; ni < 4; ++ni) sfr[ni] = sf[ni * 16 + lr];

    int w0 = wid * 32;                      // wave owns 32 pixels of the row
    i32x4 acc[2][4];
    i32x4 zero = {0, 0, 0, 0};
#pragma unroll
    for (int mi = 0; mi < 2; ++mi)
#pragma unroll
        for (int ni = 0; ni < 4; ++ni) acc[mi][ni] = zero;
    __syncthreads();

    // ---- MFMA phase: i8 K=64; rho = kh; per-mi swizzle at actual col; setprio ----
    __builtin_amdgcn_s_setprio(1);
#pragma unroll
    for (int p = 0; p < 9; ++p) {
        int kh = p / 3, kw = p % 3;         // constants after unroll
        int wp = w0 + kw + lr;
        const unsigned char* ap = AT + (size_t)(kh * WP + wp) * NC;
        const unsigned char* brow = wf + p * 8192 + l * 16;
        i32x4 bfr[2][4];
#pragma unroll
        for (int m = 0; m < 2; ++m)         // B: 16B/lane coalesced, L2-hot
#pragma unroll
            for (int ni = 0; ni < 4; ++ni)
                bfr[m][ni] = *(const i32x4*)(brow + m * 4096 + ni * 1024);
#pragma unroll
        for (int mi = 0; mi < 2; ++mi) {    // 2 x ds_read_b128 = both K-halves
            int s7m = swz7(wp + mi * 16);   // swizzle of the column actually read
            i32x4 a0 = *(const i32x4*)(ap + mi * 2048 + ((lg ^ s7m) << 4));
            i32x4 a1 = *(const i32x4*)(ap + mi * 2048 + (((lg + 4) ^ s7m) << 4));
#pragma unroll
            for (int ni = 0; ni < 4; ++ni) {
                acc[mi][ni] = __builtin_amdgcn_mfma_i32_16x16x64_i8(
                    a0, bfr[0][ni], acc[mi][ni], 0, 0, 0);
                acc[mi][ni] = __builtin_amdgcn_mfma_i32_16x16x64_i8(
                    a1, bfr[1][ni], acc[mi][ni], 0, 0, 0);
            }
        }
    }
    __builtin_amdgcn_s_setprio(0);
    __syncthreads();                        // A-tile dead; AT becomes 4 x Tt[64][36]

    // ---- epilogue: per-wave conv tile (i32 -> f32 * sf);
    //      col XOR ((row>>3)&7)<<2 on write AND read (r21-proven, in-range for 32 cols) ----
    float (*Tt)[36] = (float (*)[36])(AT + wid * 9216);
#pragma unroll
    for (int mi = 0; mi < 2; ++mi)
#pragma unroll
        for (int ni = 0; ni < 4; ++ni) {
            f32x4 cv;
            cv.x = (float)acc[mi][ni].x * sfr[ni];
            cv.y = (float)acc[mi][ni].y * sfr[ni];
            cv.z = (float)acc[mi][ni].z * sfr[ni];
            cv.w = (float)acc[mi][ni].w * sfr[ni];
            int colb = mi * 16 + lg * 4;
            int krow = ((ni * 2 + (lr >> 3)) & 7) << 2;   // ((row>>3)&7)<<2, row=ni*16+lr
            *(f32x4*)&Tt[ni * 16 + lr][colb ^ krow] = cv;
        }
    __syncthreads();

    // staging-mapped readout: thread (w4, cg) owns o in [8cg,8cg+8), pixels 4w4..+3
    int wq = w4 >> 3, w4l = w4 & 7;         // wave quarter, local pixel quad
    const float (*Ts)[36] = (const float (*)[36])(AT + wq * 9216);
    int s1 = h & 1, h2 = h >> 1;
    float* obr = out + (((size_t)nb * 256 + s1 * 2) * 64 + h2) * 64 + 2 * w4;
#pragma unroll
    for (int i = 0; i < 8; ++i) {
        int o = 8 * cg + i;
        int krd = ((o >> 3) & 7) << 2;
        f32x4 cv = *(const f32x4*)&Ts[o][(4 * w4l) ^ krd];
        float2 A = {cv.x + sc[i][0], cv.z + sc[i][2]};    // s2=0: w2 = 2w4, 2w4+1
        float2 B = {cv.y + sc[i][1], cv.w + sc[i][3]};    // s2=1
        *(float2*)(obr + (size_t)o * 16384)        = A;
        *(float2*)(obr + (size_t)o * 16384 + 4096) = B;
    }
}

extern "C" void kernel_launch(void* const* d_in, const int* in_sizes, int n_in,
                              void* d_out, int out_size, void* d_ws, size_t ws_size,
                              hipStream_t stream) {
    const float* x  = (const float*)d_in[0];
    const float* b1 = (const float*)d_in[1];
    const float* pa = (const float*)d_in[2];
    const float* b2 = (const float*)d_in[3];
    const float* cw = (const float*)d_in[4];
    const float* pw = (const float*)d_in[5];
    float* out = (float*)d_out;
    // ws layout: [0,256) sf | [256,768) theta | [768, 768+73728) wfrag
    float* sf = (float*)d_ws;
    float* theta = (float*)((char*)d_ws + 256);
    unsigned char* wfr = (unsigned char*)d_ws + 768;

    k_prep<<<288, 256, 0, stream>>>(cw, b1, pa, b2, sf, theta, wfr);
    k_fused<<<2048, 256, 0, stream>>>(x, theta, pw, wfr, sf, out);
}

// Round 25
// 72.091 us; speedup vs baseline: 2.2060x; 2.2060x over previous
//
#include <hip/hip_runtime.h>
#include <stdint.h>

typedef __attribute__((ext_vector_type(4))) float f32x4;
typedef __attribute__((ext_vector_type(4))) unsigned int u32x4;
typedef __attribute__((ext_vector_type(4))) int i32x4;

#define NB 16
#define NC 128
#define NH 128
#define NW 128
#define WP 130

__device__ __forceinline__ int swz7(int wp) { return (wp ^ (wp >> 3)) & 7; }

// ---------------- prep: wfrag (B sign bytes, i8) + sf = mean|w| + theta ----------------
// i8 K=64 layout (r16-validated): wfrag byte f = p*8192 + m*4096 + ni*1024 + l*16 + b
// o = ni*16 + (l&15), c = m*64 + (l>>4)*16 + b
__global__ __launch_bounds__(256) void k_prep(const float* __restrict__ cw,
                                              const float* __restrict__ b1,
                                              const float* __restrict__ pa,
                                              const float* __restrict__ b2,
                                              float* __restrict__ sf,
                                              float* __restrict__ theta,
                                              unsigned char* __restrict__ wf) {
    int b = blockIdx.x, t = threadIdx.x;    // 288 blocks
    int f = b * 256 + t;                    // < 73728
    int bb  = f & 15;
    int l   = (f >> 4) & 63;
    int ni  = (f >> 10) & 3;
    int m   = (f >> 12) & 1;
    int p   = f >> 13;
    int o = ni * 16 + (l & 15);
    int c = m * 64 + (l >> 4) * 16 + bb;
    float wv = cw[o * 1152 + c * 9 + p];
    wf[f] = wv > 0.f ? (unsigned char)0x01
                     : (wv < 0.f ? (unsigned char)0xFF : (unsigned char)0x00);
    if (b < 64) {                           // sf[b] = mean|w| over 1152
        __shared__ float red[4];
        const float* pp = cw + b * 1152;
        float s = 0.f;
        for (int i = t; i < 1152; i += 256) s += fabsf(pp[i]);
#pragma unroll
        for (int off = 32; off > 0; off >>= 1) s += __shfl_down(s, off);
        if ((t & 63) == 0) red[t >> 6] = s;
        __syncthreads();
        if (t == 0) sf[b] = (red[0] + red[1] + red[2] + red[3]) * (1.0f / 1152.0f);
    }
    if (b == 64 && t < NC) {                // theta: sign(prelu(v+b1)+b2) == sign(v - theta)
        float B1 = b1[t], A = pa[t], B2 = b2[t];   // prelu slope a>0 -> monotone
        theta[t] = (-B2 >= 0.f) ? (-B1 - B2) : (-B1 - B2 / A);
    }
}

__device__ __forceinline__ unsigned int pki8(float v, float th) {
    return v > th ? 0x01u : (v < th ? 0xFFu : 0u);
}

// ---------------- fused (r21 winner, final):
// 48 x-loads (3 rows) forced in flight before any pack VALU via sched_barrier(0);
// shortcut in 64 regs, mfma_i32_16x16x64_i8, Tt-tile epilogue (col ^ ((row>>3)&7)<<2
// on BOTH sides -- splits the 8-way bank classes), single out write. ----
__global__ __launch_bounds__(256, 2) void k_fused(
    const float* __restrict__ x, const float* __restrict__ theta,
    const float* __restrict__ pw, const unsigned char* __restrict__ wf,
    const float* __restrict__ sf, float* __restrict__ out) {
    __shared__ __align__(16) unsigned char AT[69632];   // staging 66560 | Tt 4x17408
    int bxr = blockIdx.x;
    int bx = (bxr & 7) * 128 + (bxr >> 3);  // XCD swizzle (1024 % 8 == 0, bijective)
    int nb = bx >> 6;
    int h2b = bx & 63;
    int t = threadIdx.x;
    int wid = t >> 6;
    int l = t & 63;
    int lr = l & 15, lg = l >> 4;

    // ---- pad columns wp=0, 129 (always zero; 64 trivial stores) ----
    if (t < 64) {
        int rho = t >> 4, side = (t >> 3) & 1, u = t & 7;
        int wp = side ? (WP - 1) : 0;
        u32x4 z = {0u, 0u, 0u, 0u};
        *(u32x4*)(AT + (size_t)(rho * WP + wp) * NC + ((u ^ swz7(wp)) << 4)) = z;
    }

    // ---- staging: thread (w4 = t&31, cg = t>>5); 3-row forced-lookahead pipeline ----
    int w4 = t & 31, cg = t >> 5;
    const float* xbase = x + ((size_t)nb * NC + cg * 16) * (NH * NW) + 4 * w4;
    f32x4 th0 = *(const f32x4*)(theta + cg * 16);
    f32x4 th1 = *(const f32x4*)(theta + cg * 16 + 4);
    f32x4 th2 = *(const f32x4*)(theta + cg * 16 + 8);
    f32x4 th3 = *(const f32x4*)(theta + cg * 16 + 12);
    f32x4 p0 = *(const f32x4*)(pw + cg * 16);
    f32x4 p1 = *(const f32x4*)(pw + cg * 16 + 4);
    f32x4 p2 = *(const f32x4*)(pw + cg * 16 + 8);
    f32x4 p3 = *(const f32x4*)(pw + cg * 16 + 12);
    float pwv[16] = {p0.x, p0.y, p0.z, p0.w, p1.x, p1.y, p1.z, p1.w,
                     p2.x, p2.y, p2.z, p2.w, p3.x, p3.y, p3.z, p3.w};
    float sc0[8][4], sc1[8][4];             // shortcut regs, statically indexed
    f32x4 XA[16], XB[16], XC[16];

#define ISSUE(XR, HH) \
    { const float* xp = xbase + (size_t)(HH) * NW; \
      _Pragma("unroll") for (int cc = 0; cc < 16; ++cc) \
          XR[cc] = *(const f32x4*)(xp + (size_t)cc * (NH * NW)); }
#define PACKROWM(RHO, XR, EM) \
    _Pragma("unroll") for (int ww = 0; ww < 4; ++ww) { \
        int wp = 4 * w4 + ww + 1; \
        u32x4 v; \
        v.x = (pki8(XR[0][ww], th0.x) | (pki8(XR[1][ww], th0.y) << 8) | \
               (pki8(XR[2][ww], th0.z) << 16) | (pki8(XR[3][ww], th0.w) << 24)) & (EM); \
        v.y = (pki8(XR[4][ww], th1.x) | (pki8(XR[5][ww], th1.y) << 8) | \
               (pki8(XR[6][ww], th1.z) << 16) | (pki8(XR[7][ww], th1.w) << 24)) & (EM); \
        v.z = (pki8(XR[8][ww], th2.x) | (pki8(XR[9][ww], th2.y) << 8) | \
               (pki8(XR[10][ww], th2.z) << 16) | (pki8(XR[11][ww], th2.w) << 24)) & (EM); \
        v.w = (pki8(XR[12][ww], th3.x) | (pki8(XR[13][ww], th3.y) << 8) | \
               (pki8(XR[14][ww], th3.z) << 16) | (pki8(XR[15][ww], th3.w) << 24)) & (EM); \
        *(u32x4*)(AT + (size_t)((RHO) * WP + wp) * NC + ((cg ^ swz7(wp)) << 4)) = v; \
    }
#define SCROW(SC, XR) \
    _Pragma("unroll") for (int i = 0; i < 8; ++i) { \
        float wa = pwv[2 * i], wb = pwv[2 * i + 1]; \
        _Pragma("unroll") for (int ww = 0; ww < 4; ++ww) \
            SC[i][ww] = wa * XR[2 * i][ww] + wb * XR[2 * i + 1][ww]; \
    }

    int hTop = (h2b > 0) ? (2 * h2b - 1) : 0;        // clamped (masked to zero below)
    int hBot = (h2b < 63) ? (2 * h2b + 2) : 127;
    unsigned emT = (h2b > 0) ? 0xFFFFFFFFu : 0u;     // block-uniform pad masks
    unsigned emB = (h2b < 63) ? 0xFFFFFFFFu : 0u;

    ISSUE(XA, hTop)                         // 48 loads in flight before any pack
    ISSUE(XB, 2 * h2b)
    ISSUE(XC, 2 * h2b + 1)
    __builtin_amdgcn_sched_barrier(0);      // pin: issues may not sink below here
    PACKROWM(0, XA, emT)
    ISSUE(XA, hBot)                         // row 3 loads overlap row 1/2 pack
    __builtin_amdgcn_sched_barrier(0);
    PACKROWM(1, XB, 0xFFFFFFFFu)
    SCROW(sc0, XB)
    PACKROWM(2, XC, 0xFFFFFFFFu)
    SCROW(sc1, XC)
    PACKROWM(3, XA, emB)

    float sfr[4];
#pragma unroll
    for (int ni = 0; ni < 4; ++ni) sfr[ni] = sf[ni * 16 + lr];

    int w0 = (wid & 1) * 64;                // output col base for this wave
    i32x4 acc[4][4];
    i32x4 zero = {0, 0, 0, 0};
#pragma unroll
    for (int mi = 0; mi < 4; ++mi)
#pragma unroll
        for (int ni = 0; ni < 4; ++ni) acc[mi][ni] = zero;
    __syncthreads();

    // ---- MFMA phase: i8 K=64; per-mi swizzle at actual col; setprio boost ----
    __builtin_amdgcn_s_setprio(1);
#pragma unroll
    for (int p = 0; p < 9; ++p) {
        int kh = p / 3, kw = p % 3;         // constants after unroll
        int rho = (wid >> 1) + kh;          // local padded row 0..3
        int wp = w0 + kw + lr;
        const unsigned char* ap = AT + (size_t)(rho * WP + wp) * NC;
        const unsigned char* brow = wf + p * 8192 + l * 16;
        i32x4 bfr[2][4];
#pragma unroll
        for (int m = 0; m < 2; ++m)         // B: 16B/lane coalesced, L2-hot
#pragma unroll
            for (int ni = 0; ni < 4; ++ni)
                bfr[m][ni] = *(const i32x4*)(brow + m * 4096 + ni * 1024);
#pragma unroll
        for (int mi = 0; mi < 4; ++mi) {    // 2 x ds_read_b128 = both K-halves
            int s7m = swz7(wp + mi * 16);   // swizzle of the column actually read
            i32x4 a0 = *(const i32x4*)(ap + mi * 2048 + ((lg ^ s7m) << 4));       // ch 16lg..+15
            i32x4 a1 = *(const i32x4*)(ap + mi * 2048 + (((lg + 4) ^ s7m) << 4)); // ch 64+16lg..
#pragma unroll
            for (int ni = 0; ni < 4; ++ni) {
                acc[mi][ni] = __builtin_amdgcn_mfma_i32_16x16x64_i8(
                    a0, bfr[0][ni], acc[mi][ni], 0, 0, 0);
                acc[mi][ni] = __builtin_amdgcn_mfma_i32_16x16x64_i8(
                    a1, bfr[1][ni], acc[mi][ni], 0, 0, 0);
            }
        }
    }
    __builtin_amdgcn_s_setprio(0);
    __syncthreads();                        // A-tile dead; AT becomes 4 x Tt[64][68]

    // ---- epilogue: full per-wave conv tile (i32 -> f32 * sf, f32x4 LDS writes)
    //      col XOR ((row>>3)&7)<<2 on write AND read: breaks the 8-way bank classes
    //      (any 16B-aligned stride has 8*stride == 0 mod 32 words). ----
    float (*Tt)[68] = (float (*)[68])(AT + wid * 17408);
#pragma unroll
    for (int mi = 0; mi < 4; ++mi)
#pragma unroll
        for (int ni = 0; ni < 4; ++ni) {
            f32x4 cv;
            cv.x = (float)acc[mi][ni].x * sfr[ni];
            cv.y = (float)acc[mi][ni].y * sfr[ni];
            cv.z = (float)acc[mi][ni].z * sfr[ni];
            cv.w = (float)acc[mi][ni].w * sfr[ni];
            int krow = ((ni * 2 + (lr >> 3)) & 7) << 2;   // ((row>>3)&7)<<2, row=ni*16+lr
            *(f32x4*)&Tt[ni * 16 + lr][(mi * 16 + lg * 4) ^ krow] = cv;
        }
    __syncthreads();

    // staging-mapped readout: thread (w4, cg) owns o in [8cg,8cg+8), cols 4w4..+3
    int wha = w4 >> 4, w4l = w4 & 15;
#define EPIROW(R2, SC) { \
    const float (*Ts)[68] = (const float (*)[68])(AT + ((R2) * 2 + wha) * 17408); \
    float* obr = out + (((size_t)nb * 256 + (R2) * 2) * 64 + h2b) * 64 + 2 * w4; \
    _Pragma("unroll") for (int i = 0; i < 8; ++i) { \
        int o = 8 * cg + i; \
        int krd = ((o >> 3) & 7) << 2; \
        f32x4 cv = *(const f32x4*)&Ts[o][(4 * w4l) ^ krd]; \
        float2 A = {cv.x + SC[i][0], cv.z + SC[i][2]}; \
        float2 B = {cv.y + SC[i][1], cv.w + SC[i][3]}; \
        *(float2*)(obr + (size_t)o * 16384)        = A; \
        *(float2*)(obr + (size_t)o * 16384 + 4096) = B; \
    } }
    EPIROW(0, sc0)
    EPIROW(1, sc1)
}

extern "C" void kernel_launch(void* const* d_in, const int* in_sizes, int n_in,
                              void* d_out, int out_size, void* d_ws, size_t ws_size,
                              hipStream_t stream) {
    const float* x  = (const float*)d_in[0];
    const float* b1 = (const float*)d_in[1];
    const float* pa = (const float*)d_in[2];
    const float* b2 = (const float*)d_in[3];
    const float* cw = (const float*)d_in[4];
    const float* pw = (const float*)d_in[5];
    float* out = (float*)d_out;
    // ws layout: [0,256) sf | [256,768) theta | [768, 768+73728) wfrag
    float* sf = (float*)d_ws;
    float* theta = (float*)((char*)d_ws + 256);
    unsigned char* wfr = (unsigned char*)d_ws + 768;

    k_prep<<<288, 256, 0, stream>>>(cw, b1, pa, b2, sf, theta, wfr);
    k_fused<<<1024, 256, 0, stream>>>(x, theta, pw, wfr, sf, out);
}